// Round 3
// baseline (587.632 us; speedup 1.0000x reference)
//
#include <hip/hip_runtime.h>

#define TT 16
#define CC 320
#define NHEADS 8
#define DH 64
#define INNER 512

typedef float f32x4 __attribute__((ext_vector_type(4)));
typedef short bf16x8 __attribute__((ext_vector_type(8)));
typedef unsigned short u16;

__device__ __forceinline__ float bf2f(u16 u){
    union { unsigned int i; float f; } v; v.i = ((unsigned int)u) << 16; return v.f;
}
__device__ __forceinline__ u16 f2bf(float f){
    union { float f; unsigned int i; } v; v.f = f;
    unsigned int x = v.i;
    return (u16)((x + 0x7fffu + ((x >> 16) & 1u)) >> 16);   // RNE
}

// ---------------- kernel 1: weights fp32 -> bf16 (no transpose needed) ----------------
__global__ __launch_bounds__(256) void k_w2bf(const float* __restrict__ wq, const float* __restrict__ wk,
                                              const float* __restrict__ wv, const float* __restrict__ wo,
                                              u16* __restrict__ oq, u16* __restrict__ ok,
                                              u16* __restrict__ ov, u16* __restrict__ oo){
    const float* s; u16* d;
    switch (blockIdx.y){
        case 0: s = wq; d = oq; break;
        case 1: s = wk; d = ok; break;
        case 2: s = wv; d = ov; break;
        default: s = wo; d = oo; break;
    }
    int i = (blockIdx.x * 256 + threadIdx.x) * 4;  // 163840 elems per matrix, grid.x=160
    f32x4 v = *(const f32x4*)(s + i);
    d[i + 0] = f2bf(v[0]); d[i + 1] = f2bf(v[1]);
    d[i + 2] = f2bf(v[2]); d[i + 3] = f2bf(v[3]);
}

// ---------------- kernel 2: transpose + LayerNorm -> xn bf16 [s][t][c] ----------------
__global__ __launch_bounds__(256) void k_ln(const float* __restrict__ x, const float* __restrict__ lnw,
                                            const float* __restrict__ lnb, u16* __restrict__ xn){
    __shared__ float tile[CC][37];      // [c][w], stride 37 words -> bank spread
    __shared__ float psum[32][36];
    __shared__ float psq[32][36];
    __shared__ float meanb[32];
    __shared__ float rstdb[32];

    int wg = blockIdx.x;                 // (b,h,t)
    int t = wg & 15, h = (wg >> 4) & 31, b = wg >> 9;
    int tid = threadIdx.x;
    const size_t base = ((size_t)(b * CC) * TT + t) * 1024 + h * 32;  // +c*16384 + w

    // pass 1: load (coalesced float4 along w), stage in LDS, partial sums
    int w4 = (tid & 7) * 4, cg = tid >> 3;        // 8 w-quads x 32 c-groups
    f32x4 s4 = {0.f,0.f,0.f,0.f}, q4 = {0.f,0.f,0.f,0.f};
    for (int i = 0; i < 10; ++i){
        int c = cg * 10 + i;
        f32x4 v = *(const f32x4*)(x + base + (size_t)c * 16384 + w4);
        tile[c][w4 + 0] = v[0]; tile[c][w4 + 1] = v[1];
        tile[c][w4 + 2] = v[2]; tile[c][w4 + 3] = v[3];
        s4 += v; q4 += v * v;
    }
    psum[cg][w4 + 0] = s4[0]; psum[cg][w4 + 1] = s4[1]; psum[cg][w4 + 2] = s4[2]; psum[cg][w4 + 3] = s4[3];
    psq [cg][w4 + 0] = q4[0]; psq [cg][w4 + 1] = q4[1]; psq [cg][w4 + 2] = q4[2]; psq [cg][w4 + 3] = q4[3];
    __syncthreads();

    if (tid < 32){
        float s = 0.f, q = 0.f;
        for (int g = 0; g < 32; ++g){ s += psum[g][tid]; q += psq[g][tid]; }
        float mean = s * (1.f / CC);
        float var  = q * (1.f / CC) - mean * mean;
        meanb[tid] = mean;
        rstdb[tid] = rsqrtf(var + 1e-5f);
    }
    __syncthreads();

    // pass 2: normalize, write bf16 coalesced along c
    int cl = tid & 63, wq_ = tid >> 6;
    float lw[5], lb[5];
    #pragma unroll
    for (int ci = 0; ci < 5; ++ci){ lw[ci] = lnw[ci * 64 + cl]; lb[ci] = lnb[ci * 64 + cl]; }
    int s_base = (b * 32 + h) * 32;
    for (int wi = 0; wi < 8; ++wi){
        int w = wq_ * 8 + wi;
        float mean = meanb[w], rstd = rstdb[w];
        size_t rowoff = ((size_t)(s_base + w) * TT + t) * CC;
        #pragma unroll
        for (int ci = 0; ci < 5; ++ci){
            int c = ci * 64 + cl;
            float nv = (tile[c][w] - mean) * rstd * lw[ci] + lb[ci];
            xn[rowoff + c] = f2bf(nv);
        }
    }
}

// ---------------- kernel 3: per-wave fused QKV + attention (no barriers) ----------------
// 1 wave = 1 sample (16 rows). 4 waves/WG, wave-private LDS scratch, VGPR<=128
// -> 16 waves/CU. Writes attn-out [m][512] bf16 to global.
__global__ __launch_bounds__(256, 4) void k_attn(const u16* __restrict__ xng,
                                                 const u16* __restrict__ wq, const u16* __restrict__ wk,
                                                 const u16* __restrict__ wv, u16* __restrict__ ao){
    __shared__ u16 qh_s[4][16][72];   // [wave][q][d]; cols 0..31 reused as P (k-pad 16..31 zeroed per head)
    __shared__ u16 kh_s[4][16][72];   // [wave][key][d]
    __shared__ u16 vt_s[4][64][36];   // [wave][d][key]; cols 16..31 zero (PV K=32 overrun)

    const int tid  = threadIdx.x;
    const int lane = tid & 63;
    const int wid  = tid >> 6;        // 0..3
    const int l15  = lane & 15;
    const int g4   = lane >> 4;       // 0..3
    const int s    = blockIdx.x * 4 + wid;
    const f32x4 zero4 = (f32x4){0.f, 0.f, 0.f, 0.f};

    // zero vt pad cols 16..31 once (wave-private, stays zero: per-head writes touch cols 0..15 only)
    #pragma unroll
    for (int i = 0; i < 16; ++i)
        vt_s[wid][i * 4 + g4][16 + l15] = 0;

    // persistent A-fragments: this sample's xn rows (16 x 320)
    bf16x8 a_f[10];
    {
        const u16* xrow = xng + ((size_t)s * TT + l15) * CC + g4 * 8;
        #pragma unroll
        for (int kk = 0; kk < 10; ++kk)
            a_f[kk] = *(const bf16x8*)(xrow + kk * 32);
    }

    u16* aor = ao + (size_t)s * TT * INNER;

    for (int hd = 0; hd < NHEADS; ++hd){
        const size_t wbase = (size_t)hd * DH * CC + (size_t)l15 * CC + g4 * 8;

        // ---- Q = xn @ Wq_h^T  (M=16, N=64, K=320) ----
        {
            f32x4 aq[4] = {zero4, zero4, zero4, zero4};
            const u16* wp = wq + wbase;
            #pragma unroll
            for (int kk = 0; kk < 10; ++kk){
                #pragma unroll
                for (int nt = 0; nt < 4; ++nt){
                    bf16x8 b = *(const bf16x8*)(wp + (size_t)nt * 16 * CC + kk * 32);
                    aq[nt] = __builtin_amdgcn_mfma_f32_16x16x32_bf16(a_f[kk], b, aq[nt], 0, 0, 0);
                }
            }
            #pragma unroll
            for (int nt = 0; nt < 4; ++nt)
                #pragma unroll
                for (int r = 0; r < 4; ++r)
                    qh_s[wid][g4 * 4 + r][nt * 16 + l15] = f2bf(aq[nt][r] * 0.125f);  // * 1/sqrt(64)
        }
        // ---- K ----
        {
            f32x4 ak[4] = {zero4, zero4, zero4, zero4};
            const u16* wp = wk + wbase;
            #pragma unroll
            for (int kk = 0; kk < 10; ++kk){
                #pragma unroll
                for (int nt = 0; nt < 4; ++nt){
                    bf16x8 b = *(const bf16x8*)(wp + (size_t)nt * 16 * CC + kk * 32);
                    ak[nt] = __builtin_amdgcn_mfma_f32_16x16x32_bf16(a_f[kk], b, ak[nt], 0, 0, 0);
                }
            }
            #pragma unroll
            for (int nt = 0; nt < 4; ++nt)
                #pragma unroll
                for (int r = 0; r < 4; ++r)
                    kh_s[wid][g4 * 4 + r][nt * 16 + l15] = f2bf(ak[nt][r]);
        }
        // ---- V^T: mfma(Wv_h, xn^T): C[d][key] ----
        {
            f32x4 av[4] = {zero4, zero4, zero4, zero4};
            const u16* wp = wv + wbase;
            #pragma unroll
            for (int kk = 0; kk < 10; ++kk){
                #pragma unroll
                for (int nt = 0; nt < 4; ++nt){
                    bf16x8 b = *(const bf16x8*)(wp + (size_t)nt * 16 * CC + kk * 32);
                    av[nt] = __builtin_amdgcn_mfma_f32_16x16x32_bf16(b, a_f[kk], av[nt], 0, 0, 0);
                }
            }
            #pragma unroll
            for (int nt = 0; nt < 4; ++nt)
                #pragma unroll
                for (int r = 0; r < 4; ++r)
                    vt_s[wid][nt * 16 + g4 * 4 + r][l15] = f2bf(av[nt][r]);
        }

        // ---- scores (16x16, K=64) ----
        f32x4 sc = zero4;
        #pragma unroll
        for (int k0 = 0; k0 < DH; k0 += 32){
            bf16x8 qa = *(const bf16x8*)(&qh_s[wid][l15][k0 + g4 * 8]);
            bf16x8 kb = *(const bf16x8*)(&kh_s[wid][l15][k0 + g4 * 8]);
            sc = __builtin_amdgcn_mfma_f32_16x16x32_bf16(qa, kb, sc, 0, 0, 0);
        }
        // softmax across keys (lanes within 16-group)
        f32x4 pr;
        #pragma unroll
        for (int r = 0; r < 4; ++r){
            float m = sc[r];
            m = fmaxf(m, __shfl_xor(m, 1)); m = fmaxf(m, __shfl_xor(m, 2));
            m = fmaxf(m, __shfl_xor(m, 4)); m = fmaxf(m, __shfl_xor(m, 8));
            float e = __expf(sc[r] - m);
            float ss = e;
            ss += __shfl_xor(ss, 1); ss += __shfl_xor(ss, 2);
            ss += __shfl_xor(ss, 4); ss += __shfl_xor(ss, 8);
            pr[r] = e / ss;
        }
        // P -> qh cols 0..31 (Q dead now); zero k-pad cols 16..31
        #pragma unroll
        for (int r = 0; r < 4; ++r){
            qh_s[wid][g4 * 4 + r][l15] = f2bf(pr[r]);
            qh_s[wid][g4 * 4 + r][16 + l15] = 0;
        }

        // ---- PV (K=32 zero-padded) ----
        bf16x8 pa = *(const bf16x8*)(&qh_s[wid][l15][g4 * 8]);
        #pragma unroll
        for (int nb = 0; nb < 4; ++nb){
            bf16x8 vb = *(const bf16x8*)(&vt_s[wid][nb * 16 + l15][g4 * 8]);
            f32x4 at = __builtin_amdgcn_mfma_f32_16x16x32_bf16(pa, vb, zero4, 0, 0, 0);
            #pragma unroll
            for (int r = 0; r < 4; ++r)
                aor[(size_t)(g4 * 4 + r) * INNER + hd * DH + nb * 16 + l15] = f2bf(at[r]);
        }
    }
}

// ---------------- kernel 3b: O-proj GEMM  proj[65536][320] = ao[65536][512] @ Wo^T + bo ----------------
// 8 waves (512 thr): wave = (mh 0..3, nh 0..1): 32 rows x 160 cols. No LDS, acc in regs.
__global__ __launch_bounds__(512, 4) void k_oproj(const u16* __restrict__ ao, const u16* __restrict__ wo,
                                                  const float* __restrict__ bo, u16* __restrict__ proj){
    const int tid  = threadIdx.x;
    const int lane = tid & 63;
    const int wid  = tid >> 6;
    const int l15  = lane & 15;
    const int g4   = lane >> 4;
    const int mh   = wid >> 1;        // 0..3
    const int nh   = wid & 1;         // 0..1
    const size_t m0 = (size_t)blockIdx.x * 128 + mh * 32;

    f32x4 acc[10][2];
    #pragma unroll
    for (int j = 0; j < 10; ++j){
        acc[j][0] = (f32x4){0.f,0.f,0.f,0.f};
        acc[j][1] = (f32x4){0.f,0.f,0.f,0.f};
    }

    const u16* ap = ao + (m0 + l15) * INNER + g4 * 8;
    const u16* wp = wo + ((size_t)(nh * 160 + l15)) * INNER + g4 * 8;

    #pragma unroll 2
    for (int kk = 0; kk < 16; ++kk){
        bf16x8 a0 = *(const bf16x8*)(ap + kk * 32);
        bf16x8 a1 = *(const bf16x8*)(ap + 16 * INNER + kk * 32);
        #pragma unroll
        for (int j = 0; j < 10; ++j){
            bf16x8 b = *(const bf16x8*)(wp + (size_t)j * 16 * INNER + kk * 32);
            acc[j][0] = __builtin_amdgcn_mfma_f32_16x16x32_bf16(a0, b, acc[j][0], 0, 0, 0);
            acc[j][1] = __builtin_amdgcn_mfma_f32_16x16x32_bf16(a1, b, acc[j][1], 0, 0, 0);
        }
    }

    #pragma unroll
    for (int j = 0; j < 10; ++j){
        int c = nh * 160 + j * 16 + l15;
        float bias = bo[c];
        #pragma unroll
        for (int mb = 0; mb < 2; ++mb){
            size_t row0 = m0 + mb * 16 + g4 * 4;
            #pragma unroll
            for (int r = 0; r < 4; ++r)
                proj[(row0 + r) * CC + c] = f2bf(acc[j][mb][r] + bias);
        }
    }
}

// ---------------- kernel 4: residual + transpose back to (b,c,t,h,w) ----------------
__global__ __launch_bounds__(256) void k_res(const u16* __restrict__ proj, const float* __restrict__ x,
                                             float* __restrict__ out){
    __shared__ u16 tile[32][328];   // [w][c]
    int wg = blockIdx.x;
    int t = wg & 15, h = (wg >> 4) & 31, b = wg >> 9;
    int tid = threadIdx.x;
    int s0 = (b * 32 + h) * 32;
    #pragma unroll
    for (int i = 0; i < 5; ++i){
        int ch = tid + 256 * i;                 // 0..1279
        int w = ch / 40, cc8 = (ch % 40) * 8;
        *(bf16x8*)(&tile[w][cc8]) = *(const bf16x8*)(proj + ((size_t)(s0 + w) * TT + t) * CC + cc8);
    }
    __syncthreads();
    int w = tid & 31, cq = tid >> 5;
    size_t base = ((size_t)(b * CC) * TT + t) * 1024 + h * 32 + w;
    for (int i = 0; i < 40; ++i){
        int c = cq * 40 + i;
        size_t idx = base + (size_t)c * 16384;
        out[idx] = x[idx] + bf2f(tile[w][c]);
    }
}

extern "C" void kernel_launch(void* const* d_in, const int* in_sizes, int n_in,
                              void* d_out, int out_size, void* d_ws, size_t ws_size,
                              hipStream_t stream){
    const float* hid = (const float*)d_in[0];
    const float* lnw = (const float*)d_in[1];
    const float* lnb = (const float*)d_in[2];
    const float* Wq  = (const float*)d_in[3];
    const float* Wk  = (const float*)d_in[4];
    const float* Wv  = (const float*)d_in[5];
    const float* Wo  = (const float*)d_in[6];
    const float* bo  = (const float*)d_in[7];

    char* ws = (char*)d_ws;
    const size_t WN = 163840;                         // elements per weight matrix
    u16* wq_b = (u16*)ws;
    u16* wk_b = wq_b + WN;
    u16* wv_b = wk_b + WN;
    u16* wo_b = wv_b + WN;
    u16* ao   = wo_b + WN;                            // 65536*512 bf16 (67 MB)
    u16* xn   = ao + (size_t)65536 * INNER;           // 65536*320 bf16 (40 MB)
    u16* proj = xn;                                   // reuse: xn dead after k_attn

    k_w2bf <<<dim3(160, 4), 256, 0, stream>>>(Wq, Wk, Wv, Wo, wq_b, wk_b, wv_b, wo_b);
    k_ln   <<<2048, 256, 0, stream>>>(hid, lnw, lnb, xn);
    k_attn <<<1024, 256, 0, stream>>>(xn, wq_b, wk_b, wv_b, ao);
    k_oproj<<<512, 512, 0, stream>>>(ao, wo_b, bo, proj);
    k_res  <<<2048, 256, 0, stream>>>(proj, hid, (float*)d_out);
}

// Round 4
// 364.558 us; speedup vs baseline: 1.6119x; 1.6119x over previous
//
#include <hip/hip_runtime.h>

#define TT 16
#define CC 320
#define NHEADS 8
#define DH 64
#define INNER 512

typedef float f32x4 __attribute__((ext_vector_type(4)));
typedef short bf16x8 __attribute__((ext_vector_type(8)));
typedef unsigned short u16;

__device__ __forceinline__ float bf2f(u16 u){
    union { unsigned int i; float f; } v; v.i = ((unsigned int)u) << 16; return v.f;
}
__device__ __forceinline__ u16 f2bf(float f){
    union { float f; unsigned int i; } v; v.f = f;
    unsigned int x = v.i;
    return (u16)((x + 0x7fffu + ((x >> 16) & 1u)) >> 16);   // RNE
}

// ---------------- kernel 1: weights fp32 -> bf16 MFMA-fragment-major ----------------
// Fragment block for W[N][K]: block = (n/16)*(K/32) + (k/32); within block,
// lane = ((k%32)>>3)*16 + (n%16), elem = k%8. A wave's B-frag (or A-frag) load
// is then base + block*512 + lane*8 : one contiguous 1KB load.
__global__ __launch_bounds__(256) void k_wfrag(const float* __restrict__ wq, const float* __restrict__ wk,
                                               const float* __restrict__ wv, const float* __restrict__ wo,
                                               u16* __restrict__ oq, u16* __restrict__ ok,
                                               u16* __restrict__ ov, u16* __restrict__ oo){
    const float* W; u16* dst; int K;
    switch (blockIdx.y){
        case 0:  W = wq; dst = oq; K = CC;    break;   // N=512, K=320
        case 1:  W = wk; dst = ok; K = CC;    break;
        case 2:  W = wv; dst = ov; K = CC;    break;
        default: W = wo; dst = oo; K = INNER; break;   // N=320, K=512
    }
    int KT = K / 32;
    int idx  = blockIdx.x * 256 + threadIdx.x;       // 20480 frags per matrix
    int lane = idx & 63;
    int blk  = idx >> 6;
    int n  = (blk / KT) * 16 + (lane & 15);
    int k0 = (blk % KT) * 32 + (lane >> 4) * 8;
    const float* src = W + (size_t)n * K + k0;
    f32x4 v0 = *(const f32x4*)src;
    f32x4 v1 = *(const f32x4*)(src + 4);
    bf16x8 o;
    o[0] = (short)f2bf(v0[0]); o[1] = (short)f2bf(v0[1]);
    o[2] = (short)f2bf(v0[2]); o[3] = (short)f2bf(v0[3]);
    o[4] = (short)f2bf(v1[0]); o[5] = (short)f2bf(v1[1]);
    o[6] = (short)f2bf(v1[2]); o[7] = (short)f2bf(v1[3]);
    *(bf16x8*)(dst + (size_t)idx * 8) = o;
}

// ---------------- kernel 2: transpose + LayerNorm -> xn bf16 fragment-major ----------------
// xn as matrix [65536][320]; sample s occupies m-tile s (16 rows = t). KT=10.
__global__ __launch_bounds__(256) void k_ln(const float* __restrict__ x, const float* __restrict__ lnw,
                                            const float* __restrict__ lnb, u16* __restrict__ xnf){
    __shared__ float tile[CC][37];      // [c][w]
    __shared__ float psum[32][36];
    __shared__ float psq[32][36];
    __shared__ float meanb[32];
    __shared__ float rstdb[32];

    int wg = blockIdx.x;                 // (b,h,t)
    int t = wg & 15, h = (wg >> 4) & 31, b = wg >> 9;
    int tid = threadIdx.x;
    const size_t base = ((size_t)(b * CC) * TT + t) * 1024 + h * 32;  // +c*16384 + w

    int w4 = (tid & 7) * 4, cg = tid >> 3;        // 8 w-quads x 32 c-groups
    f32x4 s4 = {0.f,0.f,0.f,0.f}, q4 = {0.f,0.f,0.f,0.f};
    for (int i = 0; i < 10; ++i){
        int c = cg * 10 + i;
        f32x4 v = *(const f32x4*)(x + base + (size_t)c * 16384 + w4);
        tile[c][w4 + 0] = v[0]; tile[c][w4 + 1] = v[1];
        tile[c][w4 + 2] = v[2]; tile[c][w4 + 3] = v[3];
        s4 += v; q4 += v * v;
    }
    psum[cg][w4 + 0] = s4[0]; psum[cg][w4 + 1] = s4[1]; psum[cg][w4 + 2] = s4[2]; psum[cg][w4 + 3] = s4[3];
    psq [cg][w4 + 0] = q4[0]; psq [cg][w4 + 1] = q4[1]; psq [cg][w4 + 2] = q4[2]; psq [cg][w4 + 3] = q4[3];
    __syncthreads();

    if (tid < 32){
        float s = 0.f, q = 0.f;
        for (int g = 0; g < 32; ++g){ s += psum[g][tid]; q += psq[g][tid]; }
        float mean = s * (1.f / CC);
        float var  = q * (1.f / CC) - mean * mean;
        meanb[tid] = mean;
        rstdb[tid] = rsqrtf(var + 1e-5f);
    }
    __syncthreads();

    // pass 2: normalize, write bf16 to fragment-major xn
    int cl = tid & 63, wq_ = tid >> 6;
    float lw[5], lb[5];
    #pragma unroll
    for (int ci = 0; ci < 5; ++ci){ lw[ci] = lnw[ci * 64 + cl]; lb[ci] = lnb[ci * 64 + cl]; }
    int s_base = (b * 32 + h) * 32;
    for (int wi = 0; wi < 8; ++wi){
        int w = wq_ * 8 + wi;
        float mean = meanb[w], rstd = rstdb[w];
        size_t s = s_base + w;                      // sample id = m-tile id
        #pragma unroll
        for (int ci = 0; ci < 5; ++ci){
            int c = ci * 64 + cl;                   // k index 0..319
            float nv = (tile[c][w] - mean) * rstd * lw[ci] + lb[ci];
            int kk = c >> 5;
            int lane = (((c & 31) >> 3) << 4) | t;
            xnf[((s * 10 + kk) * 64 + lane) * 8 + (c & 7)] = f2bf(nv);
        }
    }
}

// ---------------- kernel 3: per-wave fused QKV + attention (no barriers) ----------------
// 1 wave = 1 sample (16 rows = one m-tile). 4 waves/WG. All global loads are
// coalesced fragment loads. Writes attn-out fragment-major [65536][512].
__global__ __launch_bounds__(256, 4) void k_attn(const u16* __restrict__ xnf,
                                                 const u16* __restrict__ wqf, const u16* __restrict__ wkf,
                                                 const u16* __restrict__ wvf, u16* __restrict__ aof){
    __shared__ u16 qh_s[4][16][72];   // [wave][q][d]; cols 0..31 reused as P
    __shared__ u16 kh_s[4][16][72];   // [wave][key][d]; reused as attn-out staging
    __shared__ u16 vt_s[4][64][36];   // [wave][d][key]; cols 16..31 zero

    const int tid  = threadIdx.x;
    const int lane = tid & 63;
    const int wid  = tid >> 6;        // 0..3
    const int l15  = lane & 15;
    const int g4   = lane >> 4;       // 0..3
    const size_t s = (size_t)blockIdx.x * 4 + wid;   // sample = m-tile
    const f32x4 zero4 = (f32x4){0.f, 0.f, 0.f, 0.f};

    // zero vt pad cols 16..31 once (per-head writes touch cols 0..15 only)
    #pragma unroll
    for (int i = 0; i < 16; ++i)
        vt_s[wid][i * 4 + g4][16 + l15] = 0;

    // persistent A-fragments (coalesced frag loads)
    bf16x8 a_f[10];
    {
        const u16* xp = xnf + (s * 10 * 64 + lane) * 8;
        #pragma unroll
        for (int kk = 0; kk < 10; ++kk)
            a_f[kk] = *(const bf16x8*)(xp + kk * 512);
    }

    for (int hd = 0; hd < NHEADS; ++hd){
        const size_t wbase = ((size_t)hd * 4 * 10) * 512 + lane * 8;

        // ---- Q = xn @ Wq_h^T  (M=16, N=64, K=320) ----
        {
            f32x4 aq[4] = {zero4, zero4, zero4, zero4};
            const u16* wp = wqf + wbase;
            #pragma unroll
            for (int kk = 0; kk < 10; ++kk)
                #pragma unroll
                for (int nt = 0; nt < 4; ++nt){
                    bf16x8 b = *(const bf16x8*)(wp + (nt * 10 + kk) * 512);
                    aq[nt] = __builtin_amdgcn_mfma_f32_16x16x32_bf16(a_f[kk], b, aq[nt], 0, 0, 0);
                }
            #pragma unroll
            for (int nt = 0; nt < 4; ++nt)
                #pragma unroll
                for (int r = 0; r < 4; ++r)
                    qh_s[wid][g4 * 4 + r][nt * 16 + l15] = f2bf(aq[nt][r] * 0.125f);  // * 1/sqrt(64)
        }
        // ---- K ----
        {
            f32x4 ak[4] = {zero4, zero4, zero4, zero4};
            const u16* wp = wkf + wbase;
            #pragma unroll
            for (int kk = 0; kk < 10; ++kk)
                #pragma unroll
                for (int nt = 0; nt < 4; ++nt){
                    bf16x8 b = *(const bf16x8*)(wp + (nt * 10 + kk) * 512);
                    ak[nt] = __builtin_amdgcn_mfma_f32_16x16x32_bf16(a_f[kk], b, ak[nt], 0, 0, 0);
                }
            #pragma unroll
            for (int nt = 0; nt < 4; ++nt)
                #pragma unroll
                for (int r = 0; r < 4; ++r)
                    kh_s[wid][g4 * 4 + r][nt * 16 + l15] = f2bf(ak[nt][r]);
        }
        // ---- V^T: mfma(Wv_h frag as A, xn frag as B): C[d][key] ----
        {
            f32x4 av[4] = {zero4, zero4, zero4, zero4};
            const u16* wp = wvf + wbase;
            #pragma unroll
            for (int kk = 0; kk < 10; ++kk)
                #pragma unroll
                for (int nt = 0; nt < 4; ++nt){
                    bf16x8 b = *(const bf16x8*)(wp + (nt * 10 + kk) * 512);
                    av[nt] = __builtin_amdgcn_mfma_f32_16x16x32_bf16(b, a_f[kk], av[nt], 0, 0, 0);
                }
            #pragma unroll
            for (int nt = 0; nt < 4; ++nt)
                #pragma unroll
                for (int r = 0; r < 4; ++r)
                    vt_s[wid][nt * 16 + g4 * 4 + r][l15] = f2bf(av[nt][r]);
        }

        // ---- scores (16x16, K=64) ----
        f32x4 sc = zero4;
        #pragma unroll
        for (int k0 = 0; k0 < DH; k0 += 32){
            bf16x8 qa = *(const bf16x8*)(&qh_s[wid][l15][k0 + g4 * 8]);
            bf16x8 kb = *(const bf16x8*)(&kh_s[wid][l15][k0 + g4 * 8]);
            sc = __builtin_amdgcn_mfma_f32_16x16x32_bf16(qa, kb, sc, 0, 0, 0);
        }
        // softmax across keys (lanes within 16-group)
        f32x4 pr;
        #pragma unroll
        for (int r = 0; r < 4; ++r){
            float m = sc[r];
            m = fmaxf(m, __shfl_xor(m, 1)); m = fmaxf(m, __shfl_xor(m, 2));
            m = fmaxf(m, __shfl_xor(m, 4)); m = fmaxf(m, __shfl_xor(m, 8));
            float e = __expf(sc[r] - m);
            float ss = e;
            ss += __shfl_xor(ss, 1); ss += __shfl_xor(ss, 2);
            ss += __shfl_xor(ss, 4); ss += __shfl_xor(ss, 8);
            pr[r] = e / ss;
        }
        // P -> qh cols 0..31 (Q dead); zero k-pad
        #pragma unroll
        for (int r = 0; r < 4; ++r){
            qh_s[wid][g4 * 4 + r][l15] = f2bf(pr[r]);
            qh_s[wid][g4 * 4 + r][16 + l15] = 0;
        }

        // ---- PV (K=32 zero-padded) -> stage in kh_s (K dead) ----
        bf16x8 pa = *(const bf16x8*)(&qh_s[wid][l15][g4 * 8]);
        #pragma unroll
        for (int nb = 0; nb < 4; ++nb){
            bf16x8 vb = *(const bf16x8*)(&vt_s[wid][nb * 16 + l15][g4 * 8]);
            f32x4 at = __builtin_amdgcn_mfma_f32_16x16x32_bf16(pa, vb, zero4, 0, 0, 0);
            #pragma unroll
            for (int r = 0; r < 4; ++r)
                kh_s[wid][g4 * 4 + r][nb * 16 + l15] = f2bf(at[r]);
        }
        // frag-major coalesced store of attn-out (k-tiles hd*2, hd*2+1)
        #pragma unroll
        for (int kkl = 0; kkl < 2; ++kkl){
            bf16x8 o = *(const bf16x8*)(&kh_s[wid][l15][kkl * 32 + g4 * 8]);
            *(bf16x8*)(aof + ((s * 16 + hd * 2 + kkl) * 64 + lane) * 8) = o;
        }
    }
}

// ---------------- kernel 3b: O-proj GEMM  proj[65536][320] = ao[65536][512] @ Wo^T + bo ----------
// All loads are coalesced fragment loads. 8 waves: (mh 0..3, nh 0..1) -> 32 rows x 160 cols.
__global__ __launch_bounds__(512, 4) void k_oproj(const u16* __restrict__ aof, const u16* __restrict__ wof,
                                                  const float* __restrict__ bo, u16* __restrict__ proj){
    const int tid  = threadIdx.x;
    const int lane = tid & 63;
    const int wid  = tid >> 6;
    const int l15  = lane & 15;
    const int g4   = lane >> 4;
    const int mh   = wid >> 1;        // 0..3
    const int nh   = wid & 1;         // 0..1
    const size_t mt0 = (size_t)blockIdx.x * 8 + mh * 2;   // first of 2 m-tiles
    const size_t m0  = mt0 * 16;

    f32x4 acc[10][2];
    #pragma unroll
    for (int j = 0; j < 10; ++j){
        acc[j][0] = (f32x4){0.f,0.f,0.f,0.f};
        acc[j][1] = (f32x4){0.f,0.f,0.f,0.f};
    }

    const u16* ap = aof + (mt0 * 16 * 64 + lane) * 8;           // + kk*512, +16*512 for mb=1
    const u16* wp = wof + (((size_t)nh * 10 * 16) * 64 + lane) * 8;  // + (j*16+kk)*512

    #pragma unroll 2
    for (int kk = 0; kk < 16; ++kk){
        bf16x8 a0 = *(const bf16x8*)(ap + kk * 512);
        bf16x8 a1 = *(const bf16x8*)(ap + (16 + kk) * 512);
        #pragma unroll
        for (int j = 0; j < 10; ++j){
            bf16x8 b = *(const bf16x8*)(wp + (j * 16 + kk) * 512);
            acc[j][0] = __builtin_amdgcn_mfma_f32_16x16x32_bf16(a0, b, acc[j][0], 0, 0, 0);
            acc[j][1] = __builtin_amdgcn_mfma_f32_16x16x32_bf16(a1, b, acc[j][1], 0, 0, 0);
        }
    }

    #pragma unroll
    for (int j = 0; j < 10; ++j){
        int c = nh * 160 + j * 16 + l15;
        float bias = bo[c];
        #pragma unroll
        for (int mb = 0; mb < 2; ++mb){
            size_t row0 = m0 + mb * 16 + g4 * 4;
            #pragma unroll
            for (int r = 0; r < 4; ++r)
                proj[(row0 + r) * CC + c] = f2bf(acc[j][mb][r] + bias);
        }
    }
}

// ---------------- kernel 4: residual + transpose back to (b,c,t,h,w) ----------------
__global__ __launch_bounds__(256) void k_res(const u16* __restrict__ proj, const float* __restrict__ x,
                                             float* __restrict__ out){
    __shared__ u16 tile[32][328];   // [w][c]
    int wg = blockIdx.x;
    int t = wg & 15, h = (wg >> 4) & 31, b = wg >> 9;
    int tid = threadIdx.x;
    int s0 = (b * 32 + h) * 32;
    #pragma unroll
    for (int i = 0; i < 5; ++i){
        int ch = tid + 256 * i;                 // 0..1279
        int w = ch / 40, cc8 = (ch % 40) * 8;
        *(bf16x8*)(&tile[w][cc8]) = *(const bf16x8*)(proj + ((size_t)(s0 + w) * TT + t) * CC + cc8);
    }
    __syncthreads();
    int w = tid & 31, cq = tid >> 5;
    size_t base = ((size_t)(b * CC) * TT + t) * 1024 + h * 32 + w;
    for (int i = 0; i < 40; ++i){
        int c = cq * 40 + i;
        size_t idx = base + (size_t)c * 16384;
        out[idx] = x[idx] + bf2f(tile[w][c]);
    }
}

extern "C" void kernel_launch(void* const* d_in, const int* in_sizes, int n_in,
                              void* d_out, int out_size, void* d_ws, size_t ws_size,
                              hipStream_t stream){
    const float* hid = (const float*)d_in[0];
    const float* lnw = (const float*)d_in[1];
    const float* lnb = (const float*)d_in[2];
    const float* Wq  = (const float*)d_in[3];
    const float* Wk  = (const float*)d_in[4];
    const float* Wv  = (const float*)d_in[5];
    const float* Wo  = (const float*)d_in[6];
    const float* bo  = (const float*)d_in[7];

    char* ws = (char*)d_ws;
    const size_t WN = 163840;                         // elements per weight matrix
    u16* wq_f = (u16*)ws;
    u16* wk_f = wq_f + WN;
    u16* wv_f = wk_f + WN;
    u16* wo_f = wv_f + WN;
    u16* ao   = wo_f + WN;                            // 65536*512 bf16 (67 MB), frag-major
    u16* xn   = ao + (size_t)65536 * INNER;           // 65536*320 bf16 (40 MB), frag-major
    u16* proj = xn;                                   // reuse: xn dead after k_attn

    k_wfrag<<<dim3(80, 4), 256, 0, stream>>>(Wq, Wk, Wv, Wo, wq_f, wk_f, wv_f, wo_f);
    k_ln   <<<2048, 256, 0, stream>>>(hid, lnw, lnb, xn);
    k_attn <<<1024, 256, 0, stream>>>(xn, wq_f, wk_f, wv_f, ao);
    k_oproj<<<512, 512, 0, stream>>>(ao, wo_f, bo, proj);
    k_res  <<<2048, 256, 0, stream>>>(proj, hid, (float*)d_out);
}

// Round 5
// 283.826 us; speedup vs baseline: 2.0704x; 1.2844x over previous
//
#include <hip/hip_runtime.h>

#define TT 16
#define CC 320
#define NHEADS 8
#define DH 64
#define INNER 512

typedef float f32x4 __attribute__((ext_vector_type(4)));
typedef float f32x16 __attribute__((ext_vector_type(16)));
typedef short bf16x8 __attribute__((ext_vector_type(8)));
typedef unsigned short u16;

#define Z16 {0.f,0.f,0.f,0.f,0.f,0.f,0.f,0.f,0.f,0.f,0.f,0.f,0.f,0.f,0.f,0.f}

__device__ __forceinline__ float bf2f(u16 u){
    union { unsigned int i; float f; } v; v.i = ((unsigned int)u) << 16; return v.f;
}
__device__ __forceinline__ u16 f2bf(float f){
    union { float f; unsigned int i; } v; v.f = f;
    unsigned int x = v.i;
    return (u16)((x + 0x7fffu + ((x >> 16) & 1u)) >> 16);   // RNE
}

// ---------------- kernel 1a: Wq/Wk/Wv fp32 -> combined bf16 32x32x16-frag buffer ----------------
// Frag f = (hd*6 + nblk)*20 + kk ; nblk 0,1=Q  2,3=K  4,5=V (32 cols each).
// Within frag: lane = ((k%16)>>3)*32 + (n%32), elem = k%8.
__global__ __launch_bounds__(256) void k_wqkv32(const float* __restrict__ wq, const float* __restrict__ wk,
                                                const float* __restrict__ wv, u16* __restrict__ dst){
    int gid  = blockIdx.x * 256 + threadIdx.x;   // 0..61439
    int lane = gid & 63;
    int f    = gid >> 6;                          // 0..959
    int kk   = f % 20;
    int rest = f / 20;                            // 0..47
    int nblk = rest % 6;
    int hd   = rest / 6;
    const float* W = (nblk < 2) ? wq : (nblk < 4) ? wk : wv;
    int n  = hd * DH + (nblk & 1) * 32 + (lane & 31);
    int k0 = kk * 16 + (lane >> 5) * 8;
    const float* src = W + (size_t)n * CC + k0;
    f32x4 v0 = *(const f32x4*)src;
    f32x4 v1 = *(const f32x4*)(src + 4);
    bf16x8 o;
    o[0] = (short)f2bf(v0[0]); o[1] = (short)f2bf(v0[1]);
    o[2] = (short)f2bf(v0[2]); o[3] = (short)f2bf(v0[3]);
    o[4] = (short)f2bf(v1[0]); o[5] = (short)f2bf(v1[1]);
    o[6] = (short)f2bf(v1[2]); o[7] = (short)f2bf(v1[3]);
    *(bf16x8*)(dst + (size_t)gid * 8) = o;
}

// ---------------- kernel 1b: Wo fp32 -> bf16 16x16x32-frag-major (as before) ----------------
__global__ __launch_bounds__(256) void k_wo16(const float* __restrict__ wo, u16* __restrict__ dst){
    int idx  = blockIdx.x * 256 + threadIdx.x;   // 20480 frag-lanes
    int lane = idx & 63;
    int blk  = idx >> 6;
    int KT = INNER / 32;
    int n  = (blk / KT) * 16 + (lane & 15);
    int k0 = (blk % KT) * 32 + (lane >> 4) * 8;
    const float* src = wo + (size_t)n * INNER + k0;
    f32x4 v0 = *(const f32x4*)src;
    f32x4 v1 = *(const f32x4*)(src + 4);
    bf16x8 o;
    o[0] = (short)f2bf(v0[0]); o[1] = (short)f2bf(v0[1]);
    o[2] = (short)f2bf(v0[2]); o[3] = (short)f2bf(v0[3]);
    o[4] = (short)f2bf(v1[0]); o[5] = (short)f2bf(v1[1]);
    o[6] = (short)f2bf(v1[2]); o[7] = (short)f2bf(v1[3]);
    *(bf16x8*)(dst + (size_t)idx * 8) = o;
}

// ---------------- kernel 2: transpose + LayerNorm -> xn bf16 32x32x16 A-frag-major ----------------
// Sample s -> m32 tile s>>1, rows (s&1)*16 + t. Frag addr = ((m32*20 + k16)*64 + lane)*8 + k%8,
// lane = ((k%16)>>3)*32 + row.
__global__ __launch_bounds__(256) void k_ln(const float* __restrict__ x, const float* __restrict__ lnw,
                                            const float* __restrict__ lnb, u16* __restrict__ xnf){
    __shared__ float tile[CC][37];
    __shared__ float psum[32][36];
    __shared__ float psq[32][36];
    __shared__ float meanb[32];
    __shared__ float rstdb[32];

    int wg = blockIdx.x;                 // (b,h,t)
    int t = wg & 15, h = (wg >> 4) & 31, b = wg >> 9;
    int tid = threadIdx.x;
    const size_t base = ((size_t)(b * CC) * TT + t) * 1024 + h * 32;

    int w4 = (tid & 7) * 4, cg = tid >> 3;
    f32x4 s4 = {0.f,0.f,0.f,0.f}, q4 = {0.f,0.f,0.f,0.f};
    for (int i = 0; i < 10; ++i){
        int c = cg * 10 + i;
        f32x4 v = *(const f32x4*)(x + base + (size_t)c * 16384 + w4);
        tile[c][w4 + 0] = v[0]; tile[c][w4 + 1] = v[1];
        tile[c][w4 + 2] = v[2]; tile[c][w4 + 3] = v[3];
        s4 += v; q4 += v * v;
    }
    psum[cg][w4 + 0] = s4[0]; psum[cg][w4 + 1] = s4[1]; psum[cg][w4 + 2] = s4[2]; psum[cg][w4 + 3] = s4[3];
    psq [cg][w4 + 0] = q4[0]; psq [cg][w4 + 1] = q4[1]; psq [cg][w4 + 2] = q4[2]; psq [cg][w4 + 3] = q4[3];
    __syncthreads();

    if (tid < 32){
        float s = 0.f, q = 0.f;
        for (int g = 0; g < 32; ++g){ s += psum[g][tid]; q += psq[g][tid]; }
        float mean = s * (1.f / CC);
        float var  = q * (1.f / CC) - mean * mean;
        meanb[tid] = mean;
        rstdb[tid] = rsqrtf(var + 1e-5f);
    }
    __syncthreads();

    int cl = tid & 63, wq_ = tid >> 6;
    float lw[5], lb[5];
    #pragma unroll
    for (int ci = 0; ci < 5; ++ci){ lw[ci] = lnw[ci * 64 + cl]; lb[ci] = lnb[ci * 64 + cl]; }
    int s_base = (b * 32 + h) * 32;
    for (int wi = 0; wi < 8; ++wi){
        int w = wq_ * 8 + wi;
        float mean = meanb[w], rstd = rstdb[w];
        int s = s_base + w;
        int row = ((s & 1) << 4) | t;
        size_t m32 = (size_t)(s >> 1);
        #pragma unroll
        for (int ci = 0; ci < 5; ++ci){
            int c = ci * 64 + cl;
            float nv = (tile[c][w] - mean) * rstd * lw[ci] + lb[ci];
            int lane = ((((c & 15) >> 3)) << 5) | row;
            xnf[((m32 * 20 + (c >> 4)) * 64 + lane) * 8 + (c & 7)] = f2bf(nv);
        }
    }
}

// ---------------- kernel 3: fused QKV + attention ----------------
// 512 thr = 8 waves; wave owns one 32-row m-tile (2 samples), xn A-frags in regs (80 VGPR).
// QKV via 32x32x16 MFMA streaming shared frag-major weights (all waves identical B
// addresses -> L1 dedup; per-head barrier keeps waves phase-locked). Attention via
// 16x16 MFMA on wave-private LDS. Grid 256 = 1 WG/CU.
__global__ __launch_bounds__(512, 2) void k_attn(const u16* __restrict__ xnf,
                                                 const u16* __restrict__ wqkv,
                                                 u16* __restrict__ aof){
    __shared__ u16 qh[8][2][16][74];   // [wave][smp][t][d]; cols 0..31 reused for P
    __shared__ u16 kh[8][2][16][74];   // [wave][smp][key][d]; reused as PV-out staging
    __shared__ u16 vt[8][2][64][36];   // [wave][smp][d][key]; cols 16..31 zero

    const int tid  = threadIdx.x;
    const int lane = tid & 63;
    const int wid  = tid >> 6;
    const int l31  = lane & 31;
    const int h32  = lane >> 5;
    const int l15  = lane & 15;
    const int g4   = lane >> 4;
    const int m32  = blockIdx.x * 8 + wid;
    const f32x4 zero4 = {0.f, 0.f, 0.f, 0.f};

    // zero vt pad cols 16..31 (never touched by per-head writes)
    #pragma unroll
    for (int j = 0; j < 32; ++j){
        int idx = j * 64 + lane;           // 0..2047
        int smp = idx >> 10;
        int d   = (idx >> 4) & 63;
        vt[wid][smp][d][16 + (idx & 15)] = 0;
    }

    // persistent A-frags (this wave's 32 rows x 320 K)
    bf16x8 a_f[20];
    {
        const u16* xp = xnf + ((size_t)m32 * 20 * 64 + lane) * 8;
        #pragma unroll
        for (int kk = 0; kk < 20; ++kk)
            a_f[kk] = *(const bf16x8*)(xp + kk * 512);
    }

    for (int hd = 0; hd < NHEADS; ++hd){
        __syncthreads();   // pacing only (LDS is wave-private): keeps 8 waves' B streams L1-resident
        const u16* wb = wqkv + ((size_t)(hd * 6 * 20) * 64 + lane) * 8;

        // ---- pass 1: Q (nblk 0,1) + K (nblk 2,3), K=320 ----
        {
            f32x16 aq0 = Z16, aq1 = Z16, ak0 = Z16, ak1 = Z16;
            #pragma unroll
            for (int kk = 0; kk < 20; ++kk){
                bf16x8 b0 = *(const bf16x8*)(wb + (0 * 20 + kk) * 512);
                bf16x8 b1 = *(const bf16x8*)(wb + (1 * 20 + kk) * 512);
                bf16x8 b2 = *(const bf16x8*)(wb + (2 * 20 + kk) * 512);
                bf16x8 b3 = *(const bf16x8*)(wb + (3 * 20 + kk) * 512);
                aq0 = __builtin_amdgcn_mfma_f32_32x32x16_bf16(a_f[kk], b0, aq0, 0, 0, 0);
                aq1 = __builtin_amdgcn_mfma_f32_32x32x16_bf16(a_f[kk], b1, aq1, 0, 0, 0);
                ak0 = __builtin_amdgcn_mfma_f32_32x32x16_bf16(a_f[kk], b2, ak0, 0, 0, 0);
                ak1 = __builtin_amdgcn_mfma_f32_32x32x16_bf16(a_f[kk], b3, ak1, 0, 0, 0);
            }
            #pragma unroll
            for (int r = 0; r < 16; ++r){
                int row = (r & 3) + 8 * (r >> 2) + 4 * h32;   // verified 32x32 C layout
                int smp = row >> 4, tr = row & 15;
                qh[wid][smp][tr][l31]      = f2bf(aq0[r] * 0.125f);   // pre-scale 1/sqrt(64)
                qh[wid][smp][tr][32 + l31] = f2bf(aq1[r] * 0.125f);
                kh[wid][smp][tr][l31]      = f2bf(ak0[r]);
                kh[wid][smp][tr][32 + l31] = f2bf(ak1[r]);
            }
        }
        // ---- pass 2: V (nblk 4,5) -> vt transposed [d][key] ----
        {
            f32x16 av0 = Z16, av1 = Z16;
            #pragma unroll
            for (int kk = 0; kk < 20; ++kk){
                bf16x8 b4 = *(const bf16x8*)(wb + (4 * 20 + kk) * 512);
                bf16x8 b5 = *(const bf16x8*)(wb + (5 * 20 + kk) * 512);
                av0 = __builtin_amdgcn_mfma_f32_32x32x16_bf16(a_f[kk], b4, av0, 0, 0, 0);
                av1 = __builtin_amdgcn_mfma_f32_32x32x16_bf16(a_f[kk], b5, av1, 0, 0, 0);
            }
            #pragma unroll
            for (int r = 0; r < 16; ++r){
                int row = (r & 3) + 8 * (r >> 2) + 4 * h32;
                int smp = row >> 4, tr = row & 15;
                vt[wid][smp][l31][tr]      = f2bf(av0[r]);
                vt[wid][smp][32 + l31][tr] = f2bf(av1[r]);
            }
        }

        // ---- attention, per owned sample ----
        #pragma unroll
        for (int smp = 0; smp < 2; ++smp){
            f32x4 sc = zero4;
            #pragma unroll
            for (int k0 = 0; k0 < DH; k0 += 32){
                bf16x8 qa = *(const bf16x8*)(&qh[wid][smp][l15][k0 + g4 * 8]);
                bf16x8 kb = *(const bf16x8*)(&kh[wid][smp][l15][k0 + g4 * 8]);
                sc = __builtin_amdgcn_mfma_f32_16x16x32_bf16(qa, kb, sc, 0, 0, 0);
            }
            f32x4 pr;
            #pragma unroll
            for (int r = 0; r < 4; ++r){
                float m = sc[r];
                m = fmaxf(m, __shfl_xor(m, 1)); m = fmaxf(m, __shfl_xor(m, 2));
                m = fmaxf(m, __shfl_xor(m, 4)); m = fmaxf(m, __shfl_xor(m, 8));
                float e = __expf(sc[r] - m);
                float ss = e;
                ss += __shfl_xor(ss, 1); ss += __shfl_xor(ss, 2);
                ss += __shfl_xor(ss, 4); ss += __shfl_xor(ss, 8);
                pr[r] = e / ss;
            }
            // P -> qh cols 0..31 (Q dead); keys 16..31 zero
            #pragma unroll
            for (int r = 0; r < 4; ++r){
                qh[wid][smp][g4 * 4 + r][l15] = f2bf(pr[r]);
                qh[wid][smp][g4 * 4 + r][16 + l15] = 0;
            }
            // PV (K=32 zero-padded), stage into kh (dead after scores)
            bf16x8 pa = *(const bf16x8*)(&qh[wid][smp][l15][g4 * 8]);
            #pragma unroll
            for (int nb = 0; nb < 4; ++nb){
                bf16x8 vb = *(const bf16x8*)(&vt[wid][smp][nb * 16 + l15][g4 * 8]);
                f32x4 at = __builtin_amdgcn_mfma_f32_16x16x32_bf16(pa, vb, zero4, 0, 0, 0);
                #pragma unroll
                for (int r = 0; r < 4; ++r)
                    kh[wid][smp][g4 * 4 + r][nb * 16 + l15] = f2bf(at[r]);
            }
            // coalesced frag-major store of attn-out (16x16x32-frag layout for k_oproj)
            const size_t sg = (size_t)m32 * 2 + smp;
            #pragma unroll
            for (int kkl = 0; kkl < 2; ++kkl){
                bf16x8 o = *(const bf16x8*)(&kh[wid][smp][l15][kkl * 32 + g4 * 8]);
                *(bf16x8*)(aof + ((sg * 16 + hd * 2 + kkl) * 64 + lane) * 8) = o;
            }
        }
    }
}

// ---------------- kernel 3b: O-proj GEMM  proj[65536][320] = ao[65536][512] @ Wo^T + bo ----------
__global__ __launch_bounds__(512, 4) void k_oproj(const u16* __restrict__ aof, const u16* __restrict__ wof,
                                                  const float* __restrict__ bo, u16* __restrict__ proj){
    const int tid  = threadIdx.x;
    const int lane = tid & 63;
    const int wid  = tid >> 6;
    const int l15  = lane & 15;
    const int g4   = lane >> 4;
    const int mh   = wid >> 1;
    const int nh   = wid & 1;
    const size_t mt0 = (size_t)blockIdx.x * 8 + mh * 2;
    const size_t m0  = mt0 * 16;

    f32x4 acc[10][2];
    #pragma unroll
    for (int j = 0; j < 10; ++j){
        acc[j][0] = (f32x4){0.f,0.f,0.f,0.f};
        acc[j][1] = (f32x4){0.f,0.f,0.f,0.f};
    }

    const u16* ap = aof + (mt0 * 16 * 64 + lane) * 8;
    const u16* wp = wof + (((size_t)nh * 10 * 16) * 64 + lane) * 8;

    #pragma unroll 2
    for (int kk = 0; kk < 16; ++kk){
        bf16x8 a0 = *(const bf16x8*)(ap + kk * 512);
        bf16x8 a1 = *(const bf16x8*)(ap + (16 + kk) * 512);
        #pragma unroll
        for (int j = 0; j < 10; ++j){
            bf16x8 b = *(const bf16x8*)(wp + (j * 16 + kk) * 512);
            acc[j][0] = __builtin_amdgcn_mfma_f32_16x16x32_bf16(a0, b, acc[j][0], 0, 0, 0);
            acc[j][1] = __builtin_amdgcn_mfma_f32_16x16x32_bf16(a1, b, acc[j][1], 0, 0, 0);
        }
    }

    #pragma unroll
    for (int j = 0; j < 10; ++j){
        int c = nh * 160 + j * 16 + l15;
        float bias = bo[c];
        #pragma unroll
        for (int mb = 0; mb < 2; ++mb){
            size_t row0 = m0 + mb * 16 + g4 * 4;
            #pragma unroll
            for (int r = 0; r < 4; ++r)
                proj[(row0 + r) * CC + c] = f2bf(acc[j][mb][r] + bias);
        }
    }
}

// ---------------- kernel 4: residual + transpose back to (b,c,t,h,w) ----------------
__global__ __launch_bounds__(256) void k_res(const u16* __restrict__ proj, const float* __restrict__ x,
                                             float* __restrict__ out){
    __shared__ u16 tile[32][328];
    int wg = blockIdx.x;
    int t = wg & 15, h = (wg >> 4) & 31, b = wg >> 9;
    int tid = threadIdx.x;
    int s0 = (b * 32 + h) * 32;
    #pragma unroll
    for (int i = 0; i < 5; ++i){
        int ch = tid + 256 * i;
        int w = ch / 40, cc8 = (ch % 40) * 8;
        *(bf16x8*)(&tile[w][cc8]) = *(const bf16x8*)(proj + ((size_t)(s0 + w) * TT + t) * CC + cc8);
    }
    __syncthreads();
    int w = tid & 31, cq = tid >> 5;
    size_t base = ((size_t)(b * CC) * TT + t) * 1024 + h * 32 + w;
    for (int i = 0; i < 40; ++i){
        int c = cq * 40 + i;
        size_t idx = base + (size_t)c * 16384;
        out[idx] = x[idx] + bf2f(tile[w][c]);
    }
}

extern "C" void kernel_launch(void* const* d_in, const int* in_sizes, int n_in,
                              void* d_out, int out_size, void* d_ws, size_t ws_size,
                              hipStream_t stream){
    const float* hid = (const float*)d_in[0];
    const float* lnw = (const float*)d_in[1];
    const float* lnb = (const float*)d_in[2];
    const float* Wq  = (const float*)d_in[3];
    const float* Wk  = (const float*)d_in[4];
    const float* Wv  = (const float*)d_in[5];
    const float* Wo  = (const float*)d_in[6];
    const float* bo  = (const float*)d_in[7];

    char* ws = (char*)d_ws;
    u16* wqkv = (u16*)ws;                                   // 960 frags * 512 = 491,520 elems
    u16* wo_f = wqkv + (size_t)960 * 512;                   // 163,840 elems
    u16* ao   = wo_f + 163840;                              // 65536*512 (67 MB), 16-frag-major
    u16* xn   = ao + (size_t)65536 * INNER;                 // 65536*320 (40 MB), 32-frag-major
    u16* proj = xn;                                         // reuse: xn dead after k_attn

    k_wqkv32<<<240, 256, 0, stream>>>(Wq, Wk, Wv, wqkv);
    k_wo16  <<<80, 256, 0, stream>>>(Wo, wo_f);
    k_ln    <<<2048, 256, 0, stream>>>(hid, lnw, lnb, xn);
    k_attn  <<<256, 512, 0, stream>>>(xn, wqkv, ao);
    k_oproj <<<512, 512, 0, stream>>>(ao, wo_f, bo, proj);
    k_res   <<<2048, 256, 0, stream>>>(proj, hid, (float*)d_out);
}

// Round 6
// 225.341 us; speedup vs baseline: 2.6077x; 1.2595x over previous
//
#include <hip/hip_runtime.h>

#define TT 16
#define CC 320
#define NHEADS 8
#define DH 64
#define INNER 512

typedef float f32x4 __attribute__((ext_vector_type(4)));
typedef float f32x16 __attribute__((ext_vector_type(16)));
typedef short bf16x8 __attribute__((ext_vector_type(8)));
typedef unsigned short u16;

#define Z16 {0.f,0.f,0.f,0.f,0.f,0.f,0.f,0.f,0.f,0.f,0.f,0.f,0.f,0.f,0.f,0.f}

__device__ __forceinline__ float bf2f(u16 u){
    union { unsigned int i; float f; } v; v.i = ((unsigned int)u) << 16; return v.f;
}
__device__ __forceinline__ u16 f2bf(float f){
    union { float f; unsigned int i; } v; v.f = f;
    unsigned int x = v.i;
    return (u16)((x + 0x7fffu + ((x >> 16) & 1u)) >> 16);   // RNE
}

// ---------------- kernel 1a: Wq/Wk/Wv fp32 -> bf16 32x32x16-frag, CHUNK-major ----------------
// frag index f = ((hd*5 + c)*6 + nblk)*4 + kl ; kk = c*4 + kl (K-step 16)
// nblk 0,1=Q  2,3=K  4,5=V (32 cols each). Within frag: lane = ((k%16)>>3)*32 + (n%32), elem=k%8.
// One chunk (c) = 24 contiguous frags = 24 KB -> linear global_load_lds staging.
__global__ __launch_bounds__(256) void k_wqkv32(const float* __restrict__ wq, const float* __restrict__ wk,
                                                const float* __restrict__ wv, u16* __restrict__ dst){
    int gid  = blockIdx.x * 256 + threadIdx.x;   // 0..61439
    int lane = gid & 63;
    int f    = gid >> 6;                          // 0..959
    int kl   = f & 3;
    int nblk = (f >> 2) % 6;
    int c    = ((f >> 2) / 6) % 5;
    int hd   = f / 120;
    int kk   = c * 4 + kl;
    const float* W = (nblk < 2) ? wq : (nblk < 4) ? wk : wv;
    int n  = hd * DH + (nblk & 1) * 32 + (lane & 31);
    int k0 = kk * 16 + (lane >> 5) * 8;
    const float* src = W + (size_t)n * CC + k0;
    f32x4 v0 = *(const f32x4*)src;
    f32x4 v1 = *(const f32x4*)(src + 4);
    bf16x8 o;
    o[0] = (short)f2bf(v0[0]); o[1] = (short)f2bf(v0[1]);
    o[2] = (short)f2bf(v0[2]); o[3] = (short)f2bf(v0[3]);
    o[4] = (short)f2bf(v1[0]); o[5] = (short)f2bf(v1[1]);
    o[6] = (short)f2bf(v1[2]); o[7] = (short)f2bf(v1[3]);
    *(bf16x8*)(dst + (size_t)gid * 8) = o;
}

// ---------------- kernel 1b: Wo fp32 -> bf16 16x16x32-frag-major ----------------
__global__ __launch_bounds__(256) void k_wo16(const float* __restrict__ wo, u16* __restrict__ dst){
    int idx  = blockIdx.x * 256 + threadIdx.x;   // 20480 frag-lanes
    int lane = idx & 63;
    int blk  = idx >> 6;
    int KT = INNER / 32;
    int n  = (blk / KT) * 16 + (lane & 15);
    int k0 = (blk % KT) * 32 + (lane >> 4) * 8;
    const float* src = wo + (size_t)n * INNER + k0;
    f32x4 v0 = *(const f32x4*)src;
    f32x4 v1 = *(const f32x4*)(src + 4);
    bf16x8 o;
    o[0] = (short)f2bf(v0[0]); o[1] = (short)f2bf(v0[1]);
    o[2] = (short)f2bf(v0[2]); o[3] = (short)f2bf(v0[3]);
    o[4] = (short)f2bf(v1[0]); o[5] = (short)f2bf(v1[1]);
    o[6] = (short)f2bf(v1[2]); o[7] = (short)f2bf(v1[3]);
    *(bf16x8*)(dst + (size_t)idx * 8) = o;
}

// ---------------- kernel 2: transpose + LayerNorm -> xn bf16 32x32x16 A-frag-major ----------------
__global__ __launch_bounds__(256) void k_ln(const float* __restrict__ x, const float* __restrict__ lnw,
                                            const float* __restrict__ lnb, u16* __restrict__ xnf){
    __shared__ float tile[CC][37];
    __shared__ float psum[32][36];
    __shared__ float psq[32][36];
    __shared__ float meanb[32];
    __shared__ float rstdb[32];

    int wg = blockIdx.x;                 // (b,h,t)
    int t = wg & 15, h = (wg >> 4) & 31, b = wg >> 9;
    int tid = threadIdx.x;
    const size_t base = ((size_t)(b * CC) * TT + t) * 1024 + h * 32;

    int w4 = (tid & 7) * 4, cg = tid >> 3;
    f32x4 s4 = {0.f,0.f,0.f,0.f}, q4 = {0.f,0.f,0.f,0.f};
    for (int i = 0; i < 10; ++i){
        int c = cg * 10 + i;
        f32x4 v = *(const f32x4*)(x + base + (size_t)c * 16384 + w4);
        tile[c][w4 + 0] = v[0]; tile[c][w4 + 1] = v[1];
        tile[c][w4 + 2] = v[2]; tile[c][w4 + 3] = v[3];
        s4 += v; q4 += v * v;
    }
    psum[cg][w4 + 0] = s4[0]; psum[cg][w4 + 1] = s4[1]; psum[cg][w4 + 2] = s4[2]; psum[cg][w4 + 3] = s4[3];
    psq [cg][w4 + 0] = q4[0]; psq [cg][w4 + 1] = q4[1]; psq [cg][w4 + 2] = q4[2]; psq [cg][w4 + 3] = q4[3];
    __syncthreads();

    if (tid < 32){
        float s = 0.f, q = 0.f;
        for (int g = 0; g < 32; ++g){ s += psum[g][tid]; q += psq[g][tid]; }
        float mean = s * (1.f / CC);
        float var  = q * (1.f / CC) - mean * mean;
        meanb[tid] = mean;
        rstdb[tid] = rsqrtf(var + 1e-5f);
    }
    __syncthreads();

    int cl = tid & 63, wq_ = tid >> 6;
    float lw[5], lb[5];
    #pragma unroll
    for (int ci = 0; ci < 5; ++ci){ lw[ci] = lnw[ci * 64 + cl]; lb[ci] = lnb[ci * 64 + cl]; }
    int s_base = (b * 32 + h) * 32;
    for (int wi = 0; wi < 8; ++wi){
        int w = wq_ * 8 + wi;
        float mean = meanb[w], rstd = rstdb[w];
        int s = s_base + w;
        int row = ((s & 1) << 4) | t;
        size_t m32 = (size_t)(s >> 1);
        #pragma unroll
        for (int ci = 0; ci < 5; ++ci){
            int c = ci * 64 + cl;
            float nv = (tile[c][w] - mean) * rstd * lw[ci] + lb[ci];
            int lane = ((((c & 15) >> 3)) << 5) | row;
            xnf[((m32 * 20 + (c >> 4)) * 64 + lane) * 8 + (c & 7)] = f2bf(nv);
        }
    }
}

// ---------------- kernel 3: fused QKV + attention, LDS-staged weights ----------------
// 512 thr = 8 waves; wave owns one 32-row m-tile (2 samples), xn A-frags in regs.
// Per head: 5 chunks of (4 kk x 6 nblk) weight frags staged via global_load_lds into a
// double-buffered 24KB LDS region (overlaying qh/kh scratch); all 8 waves read B-frags
// from LDS (conflict-free contiguous b128). Attention phase (wave-private) unchanged.
#define QH(w,s,r,c) smem[((((w)*2+(s))*16+(r))*72) + (c)]
#define KH(w,s,r,c) smem[18432 + ((((w)*2+(s))*16+(r))*72) + (c)]
#define VT(w,s,d,k) smem[36864 + ((((w)*2+(s))*64+(d))*36) + (k)]

__global__ __launch_bounds__(512, 2) void k_attn(const u16* __restrict__ xnf,
                                                 const u16* __restrict__ wqkv,
                                                 u16* __restrict__ aof){
    // 144 KB: qh[0..18431] kh[18432..36863] vt[36864..73727] (u16 indices)
    // weight buffers overlay: buf0 = smem[0..12287], buf1 = smem[12288..24575]
    __shared__ u16 smem[73728];

    const int tid  = threadIdx.x;
    const int lane = tid & 63;
    const int wid  = tid >> 6;
    const int l31  = lane & 31;
    const int h32  = lane >> 5;
    const int l15  = lane & 15;
    const int g4   = lane >> 4;
    const int m32  = blockIdx.x * 8 + wid;
    const f32x4 zero4 = {0.f, 0.f, 0.f, 0.f};

    // zero vt pad cols 16..31 once (vt region is NOT overlaid by weight buffers)
    #pragma unroll
    for (int j = 0; j < 32; ++j){
        int idx = j * 64 + lane;           // 0..2047 per wave slice
        int smp = idx >> 10;
        int d   = (idx >> 4) & 63;
        VT(wid, smp, d, 16 + (idx & 15)) = 0;
    }

    // persistent A-frags (this wave's 32 rows x 320 K), coalesced frag loads
    bf16x8 a_f[20];
    {
        const u16* xp = xnf + ((size_t)m32 * 20 * 64 + lane) * 8;
        #pragma unroll
        for (int kk = 0; kk < 20; ++kk)
            a_f[kk] = *(const bf16x8*)(xp + kk * 512);
    }

    #define STAGE(hd_, c_) do {                                                        \
        const u16* gsrc_ = wqkv + ((size_t)((hd_) * 5 + (c_)) * 12288);                \
        u16* ldst_ = (u16*)smem + ((c_) & 1) * 12288;                                  \
        _Pragma("unroll")                                                              \
        for (int i_ = 0; i_ < 3; ++i_)                                                 \
            __builtin_amdgcn_global_load_lds(                                          \
                (const __attribute__((address_space(1))) void*)(gsrc_ + (tid + i_ * 512) * 8), \
                (__attribute__((address_space(3))) void*)(ldst_ + (tid + i_ * 512) * 8),       \
                16, 0, 0);                                                             \
    } while (0)

    for (int hd = 0; hd < NHEADS; ++hd){
        // all waves done reading qh/kh (attn of prev head) before staging clobbers them
        __builtin_amdgcn_sched_barrier(0);
        __builtin_amdgcn_s_barrier();
        __builtin_amdgcn_sched_barrier(0);

        STAGE(hd, 0);

        f32x16 acc[6];
        #pragma unroll
        for (int nb = 0; nb < 6; ++nb) acc[nb] = (f32x16)Z16;

        #pragma unroll
        for (int c = 0; c < 5; ++c){
            // drain staging (chunk c landed; cheap after first iter since it flew during compute c-1)
            asm volatile("s_waitcnt vmcnt(0)" ::: "memory");
            __builtin_amdgcn_sched_barrier(0);
            __builtin_amdgcn_s_barrier();      // chunk c visible from all waves
            __builtin_amdgcn_sched_barrier(0);
            if (c < 4) STAGE(hd, c + 1);       // prefetch next chunk during compute
            const u16* wb = (const u16*)smem + (c & 1) * 12288;
            #pragma unroll
            for (int kl = 0; kl < 4; ++kl){
                #pragma unroll
                for (int nb = 0; nb < 6; ++nb){
                    bf16x8 b = *(const bf16x8*)(wb + (nb * 4 + kl) * 512 + lane * 8);
                    acc[nb] = __builtin_amdgcn_mfma_f32_32x32x16_bf16(a_f[c * 4 + kl], b, acc[nb], 0, 0, 0);
                }
            }
            __builtin_amdgcn_sched_barrier(0);
            __builtin_amdgcn_s_barrier();      // all waves done reading buf[c&1]
            __builtin_amdgcn_sched_barrier(0);
        }

        // ---- unpack QKV accumulators to LDS (wave-private slices) ----
        #pragma unroll
        for (int r = 0; r < 16; ++r){
            int row = (r & 3) + 8 * (r >> 2) + 4 * h32;   // verified 32x32 C layout
            int smp = row >> 4, tr = row & 15;
            QH(wid, smp, tr, l31)      = f2bf(acc[0][r] * 0.125f);   // pre-scale 1/sqrt(64)
            QH(wid, smp, tr, 32 + l31) = f2bf(acc[1][r] * 0.125f);
            KH(wid, smp, tr, l31)      = f2bf(acc[2][r]);
            KH(wid, smp, tr, 32 + l31) = f2bf(acc[3][r]);
            VT(wid, smp, l31, tr)      = f2bf(acc[4][r]);
            VT(wid, smp, 32 + l31, tr) = f2bf(acc[5][r]);
        }

        // ---- attention, per owned sample (wave-private, no barriers) ----
        #pragma unroll
        for (int smp = 0; smp < 2; ++smp){
            f32x4 sc = zero4;
            #pragma unroll
            for (int k0 = 0; k0 < DH; k0 += 32){
                bf16x8 qa = *(const bf16x8*)&QH(wid, smp, l15, k0 + g4 * 8);
                bf16x8 kb = *(const bf16x8*)&KH(wid, smp, l15, k0 + g4 * 8);
                sc = __builtin_amdgcn_mfma_f32_16x16x32_bf16(qa, kb, sc, 0, 0, 0);
            }
            f32x4 pr;
            #pragma unroll
            for (int r = 0; r < 4; ++r){
                float m = sc[r];
                m = fmaxf(m, __shfl_xor(m, 1)); m = fmaxf(m, __shfl_xor(m, 2));
                m = fmaxf(m, __shfl_xor(m, 4)); m = fmaxf(m, __shfl_xor(m, 8));
                float e = __expf(sc[r] - m);
                float ss = e;
                ss += __shfl_xor(ss, 1); ss += __shfl_xor(ss, 2);
                ss += __shfl_xor(ss, 4); ss += __shfl_xor(ss, 8);
                pr[r] = e / ss;
            }
            // P -> qh cols 0..31 (Q dead); keys 16..31 zero
            #pragma unroll
            for (int r = 0; r < 4; ++r){
                QH(wid, smp, g4 * 4 + r, l15) = f2bf(pr[r]);
                QH(wid, smp, g4 * 4 + r, 16 + l15) = 0;
            }
            // PV (K=32 zero-padded), stage into kh (dead after scores)
            bf16x8 pa = *(const bf16x8*)&QH(wid, smp, l15, g4 * 8);
            #pragma unroll
            for (int nb = 0; nb < 4; ++nb){
                bf16x8 vb = *(const bf16x8*)&VT(wid, smp, nb * 16 + l15, g4 * 8);
                f32x4 at = __builtin_amdgcn_mfma_f32_16x16x32_bf16(pa, vb, zero4, 0, 0, 0);
                #pragma unroll
                for (int r = 0; r < 4; ++r)
                    KH(wid, smp, g4 * 4 + r, nb * 16 + l15) = f2bf(at[r]);
            }
            // coalesced frag-major store of attn-out (16x16x32-frag layout for k_oproj)
            const size_t sg = (size_t)m32 * 2 + smp;
            #pragma unroll
            for (int kkl = 0; kkl < 2; ++kkl){
                bf16x8 o = *(const bf16x8*)&KH(wid, smp, l15, kkl * 32 + g4 * 8);
                *(bf16x8*)(aof + ((sg * 16 + hd * 2 + kkl) * 64 + lane) * 8) = o;
            }
        }
    }
    #undef STAGE
}

// ---------------- kernel 3b: O-proj GEMM  proj[65536][320] = ao[65536][512] @ Wo^T + bo ----------
__global__ __launch_bounds__(512, 4) void k_oproj(const u16* __restrict__ aof, const u16* __restrict__ wof,
                                                  const float* __restrict__ bo, u16* __restrict__ proj){
    const int tid  = threadIdx.x;
    const int lane = tid & 63;
    const int wid  = tid >> 6;
    const int l15  = lane & 15;
    const int g4   = lane >> 4;
    const int mh   = wid >> 1;
    const int nh   = wid & 1;
    const size_t mt0 = (size_t)blockIdx.x * 8 + mh * 2;
    const size_t m0  = mt0 * 16;

    f32x4 acc[10][2];
    #pragma unroll
    for (int j = 0; j < 10; ++j){
        acc[j][0] = (f32x4){0.f,0.f,0.f,0.f};
        acc[j][1] = (f32x4){0.f,0.f,0.f,0.f};
    }

    const u16* ap = aof + (mt0 * 16 * 64 + lane) * 8;
    const u16* wp = wof + (((size_t)nh * 10 * 16) * 64 + lane) * 8;

    #pragma unroll 2
    for (int kk = 0; kk < 16; ++kk){
        bf16x8 a0 = *(const bf16x8*)(ap + kk * 512);
        bf16x8 a1 = *(const bf16x8*)(ap + (16 + kk) * 512);
        #pragma unroll
        for (int j = 0; j < 10; ++j){
            bf16x8 b = *(const bf16x8*)(wp + (j * 16 + kk) * 512);
            acc[j][0] = __builtin_amdgcn_mfma_f32_16x16x32_bf16(a0, b, acc[j][0], 0, 0, 0);
            acc[j][1] = __builtin_amdgcn_mfma_f32_16x16x32_bf16(a1, b, acc[j][1], 0, 0, 0);
        }
    }

    #pragma unroll
    for (int j = 0; j < 10; ++j){
        int c = nh * 160 + j * 16 + l15;
        float bias = bo[c];
        #pragma unroll
        for (int mb = 0; mb < 2; ++mb){
            size_t row0 = m0 + mb * 16 + g4 * 4;
            #pragma unroll
            for (int r = 0; r < 4; ++r)
                proj[(row0 + r) * CC + c] = f2bf(acc[j][mb][r] + bias);
        }
    }
}

// ---------------- kernel 4: residual + transpose back to (b,c,t,h,w) ----------------
__global__ __launch_bounds__(256) void k_res(const u16* __restrict__ proj, const float* __restrict__ x,
                                             float* __restrict__ out){
    __shared__ u16 tile[32][328];
    int wg = blockIdx.x;
    int t = wg & 15, h = (wg >> 4) & 31, b = wg >> 9;
    int tid = threadIdx.x;
    int s0 = (b * 32 + h) * 32;
    #pragma unroll
    for (int i = 0; i < 5; ++i){
        int ch = tid + 256 * i;
        int w = ch / 40, cc8 = (ch % 40) * 8;
        *(bf16x8*)(&tile[w][cc8]) = *(const bf16x8*)(proj + ((size_t)(s0 + w) * TT + t) * CC + cc8);
    }
    __syncthreads();
    int w = tid & 31, cq = tid >> 5;
    size_t base = ((size_t)(b * CC) * TT + t) * 1024 + h * 32 + w;
    for (int i = 0; i < 40; ++i){
        int c = cq * 40 + i;
        size_t idx = base + (size_t)c * 16384;
        out[idx] = x[idx] + bf2f(tile[w][c]);
    }
}

extern "C" void kernel_launch(void* const* d_in, const int* in_sizes, int n_in,
                              void* d_out, int out_size, void* d_ws, size_t ws_size,
                              hipStream_t stream){
    const float* hid = (const float*)d_in[0];
    const float* lnw = (const float*)d_in[1];
    const float* lnb = (const float*)d_in[2];
    const float* Wq  = (const float*)d_in[3];
    const float* Wk  = (const float*)d_in[4];
    const float* Wv  = (const float*)d_in[5];
    const float* Wo  = (const float*)d_in[6];
    const float* bo  = (const float*)d_in[7];

    char* ws = (char*)d_ws;
    u16* wqkv = (u16*)ws;                                   // 960 frags * 512 = 491,520 elems
    u16* wo_f = wqkv + (size_t)960 * 512;                   // 163,840 elems
    u16* ao   = wo_f + 163840;                              // 65536*512 (67 MB), 16-frag-major
    u16* xn   = ao + (size_t)65536 * INNER;                 // 65536*320 (40 MB), 32-frag-major
    u16* proj = xn;                                         // reuse: xn dead after k_attn

    k_wqkv32<<<240, 256, 0, stream>>>(Wq, Wk, Wv, wqkv);
    k_wo16  <<<80, 256, 0, stream>>>(Wo, wo_f);
    k_ln    <<<2048, 256, 0, stream>>>(hid, lnw, lnb, xn);
    k_attn  <<<256, 512, 0, stream>>>(xn, wqkv, ao);
    k_oproj <<<512, 512, 0, stream>>>(ao, wo_f, bo, proj);
    k_res   <<<2048, 256, 0, stream>>>(proj, hid, (float*)d_out);
}